// Round 17
// baseline (166.885 us; speedup 1.0000x reference)
//
#include <hip/hip_runtime.h>
#include <hip/hip_bf16.h>

typedef __attribute__((ext_vector_type(8))) short bf16x8;
typedef __attribute__((ext_vector_type(4))) float f32x4;

#define B_ 2048
#define S_ 200
#define D_ 128
#define H_ 64
#define LOG2E 1.44269504f

// ws layout
#define WS_AC 0u                  // f32 acKN[k=128][n=64] (W1a+W1c, k-major) = 32 KB
#define WS_WB 32768u              // bf16 W' [n=64][k=256] swizzled image     = 32 KB

// LDS: [0,32K) W' ; meta slots @32768 + wv*1536: [0,256) tA | [256,1088) list
#define L_META 32768
#define M_STRIDE 1536

static __device__ __forceinline__ short f2bf_hw(float f) {
    return (short)__builtin_bit_cast(unsigned short, __float2bfloat16(f));  // RNE
}

static __device__ __forceinline__ void gload16(const void* g, void* l) {
    __builtin_amdgcn_global_load_lds(
        (const __attribute__((address_space(1))) unsigned int*)g,
        (__attribute__((address_space(3))) unsigned int*)l, 16, 0, 0);
}

// ---- prep: acKN fp32 (k-major) + bf16 W' image (swizzled) — identical to R16 ----
__global__ __launch_bounds__(128)
void prep_fold(const float* __restrict__ W1, char* __restrict__ ws)
{
    const int n = blockIdx.x;       // 64
    const int k = threadIdx.x;      // 128
    float a = W1[k * H_ + n];
    float b = W1[(128 + k) * H_ + n];
    float c = W1[(256 + k) * H_ + n];
    float d = W1[(384 + k) * H_ + n];
    ((float*)(ws + WS_AC))[k * 64 + n] = a + c;
    char* img = ws + WS_WB;
    const int sw = (n & 7) << 4;
    const int kk = k >> 3, e2 = (k & 7) * 2;
    *(short*)(img + n * 512 + ((kk * 16) ^ sw) + e2)        = f2bf_hw(b - c);
    *(short*)(img + n * 512 + (((16 + kk) * 16) ^ sw) + e2) = f2bf_hw(d);
}

// ---- fused: block = 8 waves = 8 batches (ONE round, 2 waves/SIMD).
// Hist is REGISTER-staged (plain global loads, compiler vmcnt) — no LDS-DMA
// on the hot path; LDS holds only the shared W' image + per-wave meta. ----
__global__ __launch_bounds__(512, 2)
void din_fused(const float* __restrict__ tgt, const float* __restrict__ hist,
               const int* __restrict__ mask, const float* __restrict__ W2,
               const float* __restrict__ b1, const char* __restrict__ ws,
               float* __restrict__ out)
{
    __shared__ __align__(16) char L[L_META + 8 * M_STRIDE];   // 45 KB
    const int tid  = threadIdx.x;
    const int lane = tid & 63;
    const int wv   = tid >> 6;
    const int b    = blockIdx.x * 8 + wv;
    const int lo   = lane & 15;
    const int hi   = lane >> 4;
    char* Lm = L + L_META + wv * M_STRIDE;

    // --- W' staging: 8 waves x 4 KB linear gll copy (one-shot) ---
    {
        const char* wsrc = ws + WS_WB + wv * 4096 + (size_t)lane * 16u;
        #pragma unroll
        for (int i = 0; i < 4; ++i)
            gload16(wsrc + i * 1024, L + wv * 4096 + i * 1024);
    }

    // --- register loads: w2, t fragments ---
    f32x4 w2v[4];
    #pragma unroll
    for (int ng = 0; ng < 4; ++ng) {
        f32x4 wl = *(const f32x4*)(W2 + ng * 16 + hi * 4);
        w2v[ng] = (f32x4){wl[0] * LOG2E, wl[1] * LOG2E, wl[2] * LOG2E, wl[3] * LOG2E};
    }
    f32x4 tp0[4], tp1[4];
    #pragma unroll
    for (int ks = 0; ks < 4; ++ks) {
        tp0[ks] = *(const f32x4*)(tgt + (size_t)b * D_ + ks * 32 + hi * 8);
        tp1[ks] = *(const f32x4*)(tgt + (size_t)b * D_ + ks * 32 + hi * 8 + 4);
    }

    // --- in-wave mask compaction ---
    int* lst = (int*)(Lm + 256);
    int cnt = 0, uni = 0;
    {
        const int* mp = mask + (size_t)b * S_;
        int last = 0;
        #pragma unroll
        for (int c = 0; c < 4; ++c) {
            int s = c * 64 + lane;
            int m = (s < S_) ? mp[s] : 0;
            unsigned long long bal = __ballot(m != 0);
            if (m) lst[cnt + __builtin_popcountll(bal & ((1ull << lane) - 1ull))] = s;
            if (bal) last = c * 64 + (63 - __builtin_clzll(bal));
            cnt += __builtin_popcountll(bal);
        }
        if (cnt == 0) { uni = 1; cnt = S_; }
        for (int p = cnt + lane; p < 208; p += 64) lst[p] = uni ? (S_ - 1) : last;
        if (uni)
            for (int p = lane; p < S_; p += 64) lst[p] = p;
    }

    // --- in-wave exact fp32 tA (lane = n); wave-uniform t (s_loads) ---
    {
        const float* ak = (const float*)(ws + WS_AC) + lane;
        const float* tb = tgt + (size_t)b * D_;
        float ta = 0.f;
        #pragma unroll 16
        for (int d = 0; d < 128; ++d)
            ta = fmaf(tb[d], ak[d * 64], ta);
        *(float*)(Lm + lane * 4) = ta + b1[lane];
    }
    f32x4 tav[4];
    #pragma unroll
    for (int ng = 0; ng < 4; ++ng)
        tav[ng] = *(const f32x4*)(Lm + (ng * 16 + hi * 4) * 4);

    asm volatile("s_waitcnt vmcnt(0)" ::: "memory");
    __syncthreads();                          // all waves' W' quarters visible

    const int nt = (cnt + 15) >> 4;           // >= 1
    const int* ll = (const int*)(Lm + 256);

    int abase[4], akoff[8];
    #pragma unroll
    for (int ng = 0; ng < 4; ++ng) abase[ng] = (ng * 16 + lo) * 512;
    #pragma unroll
    for (int ks = 0; ks < 8; ++ks) akoff[ks] = (ks * 64 + hi * 16) ^ ((lo & 7) << 4);

    // register-staged tile load: lane (lo,hi) reads row ll[t*16+lo], 32 floats
    auto loadt = [&](f32x4 (&st)[4][2], int t) {
        int row = ll[t * 16 + lo];
        const float* hp = hist + ((size_t)b * S_ + row) * D_ + hi * 8;
        #pragma unroll
        for (int ks = 0; ks < 4; ++ks) {
            st[ks][0] = *(const f32x4*)(hp + ks * 32);
            st[ks][1] = *(const f32x4*)(hp + ks * 32 + 4);
        }
    };

    float o[4][8];
    #pragma unroll
    for (int ks = 0; ks < 4; ++ks)
        #pragma unroll
        for (int e = 0; e < 8; ++e) o[ks][e] = 0.f;
    float l = 0.f, mx = -1e30f;

    auto compt = [&](f32x4 (&st)[4][2], int t) {
        // QK: K=256 = [h | t*h]; W' frags from shared LDS (transient)
        f32x4 acc[4];
        #pragma unroll
        for (int ng = 0; ng < 4; ++ng) acc[ng] = (f32x4){0.f, 0.f, 0.f, 0.f};
        #pragma unroll
        for (int ks = 0; ks < 4; ++ks) {
            bf16x8 bh, bt;
            #pragma unroll
            for (int e = 0; e < 4; ++e) {
                bh[e]     = f2bf_hw(st[ks][0][e]);
                bh[e + 4] = f2bf_hw(st[ks][1][e]);
                bt[e]     = f2bf_hw(tp0[ks][e] * st[ks][0][e]);   // fp32 product, RNE
                bt[e + 4] = f2bf_hw(tp1[ks][e] * st[ks][1][e]);
            }
            #pragma unroll
            for (int ng = 0; ng < 4; ++ng) {
                bf16x8 afh = *(const bf16x8*)(L + abase[ng] + akoff[ks]);
                acc[ng] = __builtin_amdgcn_mfma_f32_16x16x32_bf16(afh, bh, acc[ng], 0, 0, 0);
            }
            #pragma unroll
            for (int ng = 0; ng < 4; ++ng) {
                bf16x8 afd = *(const bf16x8*)(L + abase[ng] + akoff[ks + 4]);
                acc[ng] = __builtin_amdgcn_mfma_f32_16x16x32_bf16(afd, bt, acc[ng], 0, 0, 0);
            }
        }
        // lane-local relu-dot over 16 n-values; s-row = t*16 + lo
        float s0 = 0.f, s1 = 0.f, s2 = 0.f, s3 = 0.f;
        #pragma unroll
        for (int e = 0; e < 4; ++e) {
            s0 = fmaf(fmaxf(acc[0][e] + tav[0][e], 0.f), w2v[0][e], s0);
            s1 = fmaf(fmaxf(acc[1][e] + tav[1][e], 0.f), w2v[1][e], s1);
            s2 = fmaf(fmaxf(acc[2][e] + tav[2][e], 0.f), w2v[2][e], s2);
            s3 = fmaf(fmaxf(acc[3][e] + tav[3][e], 0.f), w2v[3][e], s3);
        }
        float sum = (s0 + s1) + (s2 + s3);
        sum += __shfl_xor(sum, 16);
        sum += __shfl_xor(sum, 32);
        const bool valid = (t * 16 + lo) < cnt;
        float lg = uni ? (valid ? 0.f : -1e30f) : (valid ? sum : -1e30f);
        float tm = lg;
        tm = fmaxf(tm, __shfl_xor(tm, 1));
        tm = fmaxf(tm, __shfl_xor(tm, 2));
        tm = fmaxf(tm, __shfl_xor(tm, 4));
        tm = fmaxf(tm, __shfl_xor(tm, 8));
        if (tm > mx + 11.5f) {                // defer-rescale (T13)
            float rsc = exp2f(mx - tm);
            #pragma unroll
            for (int ks = 0; ks < 4; ++ks)
                #pragma unroll
                for (int e = 0; e < 8; ++e) o[ks][e] *= rsc;
            l *= rsc;
            mx = tm;
        }
        float p = valid ? exp2f(lg - mx) : 0.f;
        l += p;
        // PV from the live st registers
        #pragma unroll
        for (int ks = 0; ks < 4; ++ks) {
            o[ks][0] = fmaf(p, st[ks][0][0], o[ks][0]);
            o[ks][1] = fmaf(p, st[ks][0][1], o[ks][1]);
            o[ks][2] = fmaf(p, st[ks][0][2], o[ks][2]);
            o[ks][3] = fmaf(p, st[ks][0][3], o[ks][3]);
            o[ks][4] = fmaf(p, st[ks][1][0], o[ks][4]);
            o[ks][5] = fmaf(p, st[ks][1][1], o[ks][5]);
            o[ks][6] = fmaf(p, st[ks][1][2], o[ks][6]);
            o[ks][7] = fmaf(p, st[ks][1][3], o[ks][7]);
        }
    };

    // --- per-wave register double-buffered pipeline (no barriers, no asm waits) ---
    f32x4 stA[4][2], stB[4][2];
    loadt(stA, 0);
    if (nt > 1) loadt(stB, 1);
    int t = 0;
    #pragma unroll 1
    for (; t + 1 < nt; t += 2) {
        compt(stA, t);
        if (t + 2 < nt) loadt(stA, t + 2);
        compt(stB, t + 1);
        if (t + 3 < nt) loadt(stB, t + 3);
    }
    if (t < nt) compt(stA, t);

    // ---- epilogue: lo-reduce, direct stores ----
    #pragma unroll
    for (int ks = 0; ks < 4; ++ks)
        #pragma unroll
        for (int e = 0; e < 8; ++e) {
            float v = o[ks][e];
            v += __shfl_xor(v, 1);
            v += __shfl_xor(v, 2);
            v += __shfl_xor(v, 4);
            v += __shfl_xor(v, 8);
            o[ks][e] = v;
        }
    l += __shfl_xor(l, 1);
    l += __shfl_xor(l, 2);
    l += __shfl_xor(l, 4);
    l += __shfl_xor(l, 8);

    const float inv = 1.0f / l;               // mx, b2 cancel in softmax
    if (lo == 0) {
        float* op = out + (size_t)b * D_ + hi * 8;
        #pragma unroll
        for (int ks = 0; ks < 4; ++ks) {
            *(f32x4*)(op + ks * 32)     = (f32x4){o[ks][0] * inv, o[ks][1] * inv,
                                                  o[ks][2] * inv, o[ks][3] * inv};
            *(f32x4*)(op + ks * 32 + 4) = (f32x4){o[ks][4] * inv, o[ks][5] * inv,
                                                  o[ks][6] * inv, o[ks][7] * inv};
        }
    }
}

extern "C" void kernel_launch(void* const* d_in, const int* in_sizes, int n_in,
                              void* d_out, int out_size, void* d_ws, size_t ws_size,
                              hipStream_t stream) {
    const float* tgt  = (const float*)d_in[0];
    const float* hist = (const float*)d_in[1];
    const int*   mask = (const int*)d_in[2];
    const float* W1   = (const float*)d_in[3];
    const float* b1   = (const float*)d_in[4];
    const float* W2   = (const float*)d_in[5];
    const float* b2   = (const float*)d_in[6];
    (void)b2;  // cancels in softmax
    float* out = (float*)d_out;
    char* ws = (char*)d_ws;

    prep_fold<<<64, 128, 0, stream>>>(W1, ws);
    din_fused<<<B_ / 8, 512, 0, stream>>>(tgt, hist, mask, W2, b1, ws, out);
}

// Round 18
// 49.347 us; speedup vs baseline: 3.3819x; 3.3819x over previous
//
#include <hip/hip_runtime.h>
#include <hip/hip_bf16.h>

typedef __attribute__((ext_vector_type(8))) short bf16x8;
typedef __attribute__((ext_vector_type(4))) float f32x4;

#define B_ 2048
#define S_ 200
#define D_ 128
#define H_ 64
#define LOG2E 1.44269504f

// ws layout
#define WS_AC 0u                  // f32 acKN[k=128][n=64] (W1a+W1c, k-major) = 32 KB
#define WS_WB 32768u              // bf16 W' [n=64][k=256] swizzled image     = 32 KB

// LDS: [0,32K) W' ; meta slots @32768 + wv*1536: [0,256) tA | [256,1088) list
#define L_META 32768
#define M_STRIDE 1536

static __device__ __forceinline__ short f2bf_hw(float f) {
    return (short)__builtin_bit_cast(unsigned short, __float2bfloat16(f));  // RNE
}

static __device__ __forceinline__ void gload16(const void* g, void* l) {
    __builtin_amdgcn_global_load_lds(
        (const __attribute__((address_space(1))) unsigned int*)g,
        (__attribute__((address_space(3))) unsigned int*)l, 16, 0, 0);
}

// ---- prep: acKN fp32 (k-major) + bf16 W' image (swizzled) — identical to R16 ----
__global__ __launch_bounds__(128)
void prep_fold(const float* __restrict__ W1, char* __restrict__ ws)
{
    const int n = blockIdx.x;       // 64
    const int k = threadIdx.x;      // 128
    float a = W1[k * H_ + n];
    float b = W1[(128 + k) * H_ + n];
    float c = W1[(256 + k) * H_ + n];
    float d = W1[(384 + k) * H_ + n];
    ((float*)(ws + WS_AC))[k * 64 + n] = a + c;
    char* img = ws + WS_WB;
    const int sw = (n & 7) << 4;
    const int kk = k >> 3, e2 = (k & 7) * 2;
    *(short*)(img + n * 512 + ((kk * 16) ^ sw) + e2)        = f2bf_hw(b - c);
    *(short*)(img + n * 512 + (((16 + kk) * 16) ^ sw) + e2) = f2bf_hw(d);
}

// ---- fused: block = 4 waves = 4 batches; REGISTER-staged hist (plain global
// loads, compiler vmcnt). amdgpu_waves_per_eu(1,1) pins the 256-VGPR budget
// (R7/R17 lesson: launch_bounds' 2nd arg does NOT). 1 block/CU, 2 rounds —
// same occupancy as R16; ONLY the staging path differs (gll-queue A/B). ----
__global__ __launch_bounds__(256) __attribute__((amdgpu_waves_per_eu(1, 1)))
void din_fused(const float* __restrict__ tgt, const float* __restrict__ hist,
               const int* __restrict__ mask, const float* __restrict__ W2,
               const float* __restrict__ b1, const char* __restrict__ ws,
               float* __restrict__ out)
{
    __shared__ __align__(16) char L[L_META + 4 * M_STRIDE];   // 38 KB
    const int tid  = threadIdx.x;
    const int lane = tid & 63;
    const int wv   = tid >> 6;
    const int b    = blockIdx.x * 4 + wv;
    const int lo   = lane & 15;
    const int hi   = lane >> 4;
    char* Lm = L + L_META + wv * M_STRIDE;

    // --- W' staging: 4 waves x 8 KB linear gll copy (one-shot) ---
    {
        const char* wsrc = ws + WS_WB + wv * 8192 + (size_t)lane * 16u;
        #pragma unroll
        for (int i = 0; i < 8; ++i)
            gload16(wsrc + i * 1024, L + wv * 8192 + i * 1024);
    }

    // --- register loads: w2, t fragments ---
    f32x4 w2v[4];
    #pragma unroll
    for (int ng = 0; ng < 4; ++ng) {
        f32x4 wl = *(const f32x4*)(W2 + ng * 16 + hi * 4);
        w2v[ng] = (f32x4){wl[0] * LOG2E, wl[1] * LOG2E, wl[2] * LOG2E, wl[3] * LOG2E};
    }
    f32x4 tp0[4], tp1[4];
    #pragma unroll
    for (int ks = 0; ks < 4; ++ks) {
        tp0[ks] = *(const f32x4*)(tgt + (size_t)b * D_ + ks * 32 + hi * 8);
        tp1[ks] = *(const f32x4*)(tgt + (size_t)b * D_ + ks * 32 + hi * 8 + 4);
    }

    // --- in-wave mask compaction ---
    int* lst = (int*)(Lm + 256);
    int cnt = 0, uni = 0;
    {
        const int* mp = mask + (size_t)b * S_;
        int last = 0;
        #pragma unroll
        for (int c = 0; c < 4; ++c) {
            int s = c * 64 + lane;
            int m = (s < S_) ? mp[s] : 0;
            unsigned long long bal = __ballot(m != 0);
            if (m) lst[cnt + __builtin_popcountll(bal & ((1ull << lane) - 1ull))] = s;
            if (bal) last = c * 64 + (63 - __builtin_clzll(bal));
            cnt += __builtin_popcountll(bal);
        }
        if (cnt == 0) { uni = 1; cnt = S_; }
        for (int p = cnt + lane; p < 208; p += 64) lst[p] = uni ? (S_ - 1) : last;
        if (uni)
            for (int p = lane; p < S_; p += 64) lst[p] = p;
    }

    // --- in-wave exact fp32 tA (lane = n); wave-uniform t (s_loads) ---
    {
        const float* ak = (const float*)(ws + WS_AC) + lane;
        const float* tb = tgt + (size_t)b * D_;
        float ta = 0.f;
        #pragma unroll 16
        for (int d = 0; d < 128; ++d)
            ta = fmaf(tb[d], ak[d * 64], ta);
        *(float*)(Lm + lane * 4) = ta + b1[lane];
    }
    f32x4 tav[4];
    #pragma unroll
    for (int ng = 0; ng < 4; ++ng)
        tav[ng] = *(const f32x4*)(Lm + (ng * 16 + hi * 4) * 4);

    asm volatile("s_waitcnt vmcnt(0)" ::: "memory");
    __syncthreads();                          // all waves' W' quarters visible

    const int nt = (cnt + 15) >> 4;           // >= 1
    const int* ll = (const int*)(Lm + 256);

    int abase[4], akoff[8];
    #pragma unroll
    for (int ng = 0; ng < 4; ++ng) abase[ng] = (ng * 16 + lo) * 512;
    #pragma unroll
    for (int ks = 0; ks < 8; ++ks) akoff[ks] = (ks * 64 + hi * 16) ^ ((lo & 7) << 4);

    // register-staged tile load: lane (lo,hi) reads row ll[t*16+lo], 32 floats
    auto loadt = [&](f32x4 (&st)[4][2], int t) {
        int row = ll[t * 16 + lo];
        const float* hp = hist + ((size_t)b * S_ + row) * D_ + hi * 8;
        #pragma unroll
        for (int ks = 0; ks < 4; ++ks) {
            st[ks][0] = *(const f32x4*)(hp + ks * 32);
            st[ks][1] = *(const f32x4*)(hp + ks * 32 + 4);
        }
    };

    float o[4][8];
    #pragma unroll
    for (int ks = 0; ks < 4; ++ks)
        #pragma unroll
        for (int e = 0; e < 8; ++e) o[ks][e] = 0.f;
    float l = 0.f, mx = -1e30f;

    auto compt = [&](f32x4 (&st)[4][2], int t) {
        // QK: K=256 = [h | t*h]; W' frags from shared LDS (transient reads)
        f32x4 acc[4];
        #pragma unroll
        for (int ng = 0; ng < 4; ++ng) acc[ng] = (f32x4){0.f, 0.f, 0.f, 0.f};
        #pragma unroll
        for (int ks = 0; ks < 4; ++ks) {
            bf16x8 bh, bt;
            #pragma unroll
            for (int e = 0; e < 4; ++e) {
                bh[e]     = f2bf_hw(st[ks][0][e]);
                bh[e + 4] = f2bf_hw(st[ks][1][e]);
                bt[e]     = f2bf_hw(tp0[ks][e] * st[ks][0][e]);   // fp32 product, RNE
                bt[e + 4] = f2bf_hw(tp1[ks][e] * st[ks][1][e]);
            }
            #pragma unroll
            for (int ng = 0; ng < 4; ++ng) {
                bf16x8 afh = *(const bf16x8*)(L + abase[ng] + akoff[ks]);
                acc[ng] = __builtin_amdgcn_mfma_f32_16x16x32_bf16(afh, bh, acc[ng], 0, 0, 0);
            }
            #pragma unroll
            for (int ng = 0; ng < 4; ++ng) {
                bf16x8 afd = *(const bf16x8*)(L + abase[ng] + akoff[ks + 4]);
                acc[ng] = __builtin_amdgcn_mfma_f32_16x16x32_bf16(afd, bt, acc[ng], 0, 0, 0);
            }
        }
        // lane-local relu-dot over 16 n-values; s-row = t*16 + lo
        float s0 = 0.f, s1 = 0.f, s2 = 0.f, s3 = 0.f;
        #pragma unroll
        for (int e = 0; e < 4; ++e) {
            s0 = fmaf(fmaxf(acc[0][e] + tav[0][e], 0.f), w2v[0][e], s0);
            s1 = fmaf(fmaxf(acc[1][e] + tav[1][e], 0.f), w2v[1][e], s1);
            s2 = fmaf(fmaxf(acc[2][e] + tav[2][e], 0.f), w2v[2][e], s2);
            s3 = fmaf(fmaxf(acc[3][e] + tav[3][e], 0.f), w2v[3][e], s3);
        }
        float sum = (s0 + s1) + (s2 + s3);
        sum += __shfl_xor(sum, 16);
        sum += __shfl_xor(sum, 32);
        const bool valid = (t * 16 + lo) < cnt;
        float lg = uni ? (valid ? 0.f : -1e30f) : (valid ? sum : -1e30f);
        float tm = lg;
        tm = fmaxf(tm, __shfl_xor(tm, 1));
        tm = fmaxf(tm, __shfl_xor(tm, 2));
        tm = fmaxf(tm, __shfl_xor(tm, 4));
        tm = fmaxf(tm, __shfl_xor(tm, 8));
        if (tm > mx + 11.5f) {                // defer-rescale (T13)
            float rsc = exp2f(mx - tm);
            #pragma unroll
            for (int ks = 0; ks < 4; ++ks)
                #pragma unroll
                for (int e = 0; e < 8; ++e) o[ks][e] *= rsc;
            l *= rsc;
            mx = tm;
        }
        float p = valid ? exp2f(lg - mx) : 0.f;
        l += p;
        // PV from the live st registers
        #pragma unroll
        for (int ks = 0; ks < 4; ++ks) {
            o[ks][0] = fmaf(p, st[ks][0][0], o[ks][0]);
            o[ks][1] = fmaf(p, st[ks][0][1], o[ks][1]);
            o[ks][2] = fmaf(p, st[ks][0][2], o[ks][2]);
            o[ks][3] = fmaf(p, st[ks][0][3], o[ks][3]);
            o[ks][4] = fmaf(p, st[ks][1][0], o[ks][4]);
            o[ks][5] = fmaf(p, st[ks][1][1], o[ks][5]);
            o[ks][6] = fmaf(p, st[ks][1][2], o[ks][6]);
            o[ks][7] = fmaf(p, st[ks][1][3], o[ks][7]);
        }
    };

    // --- per-wave register double-buffered pipeline (no barriers, no asm waits) ---
    f32x4 stA[4][2], stB[4][2];
    loadt(stA, 0);
    if (nt > 1) loadt(stB, 1);
    int t = 0;
    #pragma unroll 1
    for (; t + 1 < nt; t += 2) {
        compt(stA, t);
        if (t + 2 < nt) loadt(stA, t + 2);
        compt(stB, t + 1);
        if (t + 3 < nt) loadt(stB, t + 3);
    }
    if (t < nt) compt(stA, t);

    // ---- epilogue: lo-reduce, direct stores ----
    #pragma unroll
    for (int ks = 0; ks < 4; ++ks)
        #pragma unroll
        for (int e = 0; e < 8; ++e) {
            float v = o[ks][e];
            v += __shfl_xor(v, 1);
            v += __shfl_xor(v, 2);
            v += __shfl_xor(v, 4);
            v += __shfl_xor(v, 8);
            o[ks][e] = v;
        }
    l += __shfl_xor(l, 1);
    l += __shfl_xor(l, 2);
    l += __shfl_xor(l, 4);
    l += __shfl_xor(l, 8);

    const float inv = 1.0f / l;               // mx, b2 cancel in softmax
    if (lo == 0) {
        float* op = out + (size_t)b * D_ + hi * 8;
        #pragma unroll
        for (int ks = 0; ks < 4; ++ks) {
            *(f32x4*)(op + ks * 32)     = (f32x4){o[ks][0] * inv, o[ks][1] * inv,
                                                  o[ks][2] * inv, o[ks][3] * inv};
            *(f32x4*)(op + ks * 32 + 4) = (f32x4){o[ks][4] * inv, o[ks][5] * inv,
                                                  o[ks][6] * inv, o[ks][7] * inv};
        }
    }
}

extern "C" void kernel_launch(void* const* d_in, const int* in_sizes, int n_in,
                              void* d_out, int out_size, void* d_ws, size_t ws_size,
                              hipStream_t stream) {
    const float* tgt  = (const float*)d_in[0];
    const float* hist = (const float*)d_in[1];
    const int*   mask = (const int*)d_in[2];
    const float* W1   = (const float*)d_in[3];
    const float* b1   = (const float*)d_in[4];
    const float* W2   = (const float*)d_in[5];
    const float* b2   = (const float*)d_in[6];
    (void)b2;  // cancels in softmax
    float* out = (float*)d_out;
    char* ws = (char*)d_ws;

    prep_fold<<<64, 128, 0, stream>>>(W1, ws);
    din_fused<<<B_ / 4, 256, 0, stream>>>(tgt, hist, mask, W2, b1, ws, out);
}